// Round 1
// baseline (216.936 us; speedup 1.0000x reference)
//
#include <hip/hip_runtime.h>
#include <stdint.h>

// ---------------- common helpers ----------------
typedef __attribute__((ext_vector_type(4))) float f32x4;
typedef __attribute__((ext_vector_type(8))) short bf16x8;

__device__ __forceinline__ unsigned short f2bf(float f) {
  union { float f; unsigned int u; } v; v.f = f;
  unsigned int r = v.u + 0x7fffu + ((v.u >> 16) & 1u);  // RNE
  return (unsigned short)(r >> 16);
}
__device__ __forceinline__ float bflo(unsigned int w) { return __uint_as_float(w << 16); }
__device__ __forceinline__ float bfhi(unsigned int w) { return __uint_as_float(w & 0xffff0000u); }
__device__ __forceinline__ unsigned int packbf2(float a, float b) {
  return (unsigned int)f2bf(a) | ((unsigned int)f2bf(b) << 16);
}

#define LDK 200  // LDS row pitch (bf16 elems): 192+8 -> 400B rows, 16B aligned, uniform bank spread
#define QSCALE 0.17677669529663689f  // 32^-0.5

// ---------------- kernel 1: qkv GEMM ----------------
// qkv[pixel][576] = x_nchw_transposed @ qkv_w^T + qkv_b  (bf16 out, q channels pre-scaled)
__global__ __launch_bounds__(256) void qkv_gemm(
    const float* __restrict__ x, const float* __restrict__ w,
    const float* __restrict__ bias, unsigned short* __restrict__ qkv) {
  __shared__ unsigned short Al[64 * LDK];
  __shared__ unsigned short Bl[64 * LDK];
  const int t = threadIdx.x;
  const int tm = blockIdx.x;        // 512 pixel tiles (64 px each, never crosses batch: 4096%64==0)
  const int n0 = blockIdx.y * 64;   // 9 channel tiles
  const int bb = (tm * 64) >> 12, hw0 = (tm * 64) & 4095;
  const float* xb = x + (size_t)bb * 192 * 4096 + hw0;

  // stage A: 64 pixels x 192 channels, transpose from NCHW (coalesced global reads)
  for (int j = 0; j < 12288; j += 256) {
    int idx = j + t;
    int m = idx & 63, c = idx >> 6;
    Al[m * LDK + c] = f2bf(xb[c * 4096 + m]);
  }
  // stage B: qkv_w rows [n][k] (already B^T layout), fold q-scale
  for (int j = 0; j < 3072; j += 256) {
    int idx = j + t;
    int n = idx / 48, k = (idx % 48) * 4;
    int gn = n0 + n;
    float sc = ((gn % 192) < 64) ? QSCALE : 1.0f;
    const float4 wv = *(const float4*)(w + gn * 192 + k);
    ushort4 pk;
    pk.x = f2bf(wv.x * sc); pk.y = f2bf(wv.y * sc);
    pk.z = f2bf(wv.z * sc); pk.w = f2bf(wv.w * sc);
    *(ushort4*)&Bl[n * LDK + k] = pk;
  }
  __syncthreads();

  const int lane = t & 63, wid = t >> 6;
  const int wm = (wid >> 1) * 32, wn = (wid & 1) * 32;  // 2x2 waves, 32x32 each
  const int lr = lane & 15, kb = (lane >> 4) * 8;
  f32x4 acc[2][2];
  #pragma unroll
  for (int i = 0; i < 2; ++i)
    #pragma unroll
    for (int j = 0; j < 2; ++j)
      #pragma unroll
      for (int r = 0; r < 4; ++r) acc[i][j][r] = 0.0f;

  #pragma unroll
  for (int kk = 0; kk < 192; kk += 32) {
    bf16x8 a0 = *(const bf16x8*)&Al[(wm + lr) * LDK + kk + kb];
    bf16x8 a1 = *(const bf16x8*)&Al[(wm + 16 + lr) * LDK + kk + kb];
    bf16x8 b0 = *(const bf16x8*)&Bl[(wn + lr) * LDK + kk + kb];
    bf16x8 b1 = *(const bf16x8*)&Bl[(wn + 16 + lr) * LDK + kk + kb];
    acc[0][0] = __builtin_amdgcn_mfma_f32_16x16x32_bf16(a0, b0, acc[0][0], 0, 0, 0);
    acc[0][1] = __builtin_amdgcn_mfma_f32_16x16x32_bf16(a0, b1, acc[0][1], 0, 0, 0);
    acc[1][0] = __builtin_amdgcn_mfma_f32_16x16x32_bf16(a1, b0, acc[1][0], 0, 0, 0);
    acc[1][1] = __builtin_amdgcn_mfma_f32_16x16x32_bf16(a1, b1, acc[1][1], 0, 0, 0);
  }

  // D layout: col = lane&15, row = (lane>>4)*4 + reg  [m89-verified]
  unsigned short* op = qkv + (size_t)(tm * 64) * 576 + n0;
  const int r0 = (lane >> 4) * 4;
  #pragma unroll
  for (int i = 0; i < 2; ++i)
    #pragma unroll
    for (int j = 0; j < 2; ++j) {
      int col = wn + j * 16 + lr;
      int gn = n0 + col;
      float bs = bias[gn] * (((gn % 192) < 64) ? QSCALE : 1.0f);
      #pragma unroll
      for (int r = 0; r < 4; ++r) {
        int row = wm + i * 16 + r0 + r;
        op[row * 576 + col] = f2bf(acc[i][j][r] + bs);
      }
    }
}

// ---------------- kernel 2: neighborhood attention (all 3 branches) ----------------
template <int K, int DIL>
__device__ __forceinline__ void natten_branch(
    const unsigned short* __restrict__ qkv, const float* __restrict__ rpb,
    unsigned short* __restrict__ yo, const int branch) {
  constexpr int RW = 2 * K - 1;
  __shared__ float rs[RW * RW];
  const int t = threadIdx.x;
  const int head = blockIdx.y & 1, bb = blockIdx.y >> 1;
  for (int i = t; i < RW * RW; i += 256) rs[i] = rpb[head * RW * RW + i];
  __syncthreads();
  const int h = ((blockIdx.x >> 2) << 4) + (t >> 4);
  const int w = ((blockIdx.x & 3) << 4) + (t & 15);

  // axis indices (NATTEN with dilation); h-axis kept scalar (kh loop rolled),
  // w-axis in arrays (kw loop unrolled -> compile-time indexed, stays in regs)
  int s0h, gh, iih;
  {
    gh = h % DIL; iih = h / DIL;
    const int Lg = (64 - gh + DIL - 1) / DIL;
    s0h = iih - K / 2; if (s0h < 0) s0h = 0; if (s0h > Lg - K) s0h = Lg - K;
  }
  int nw[K], bw[K];
  {
    const int g = w % DIL, ii = w / DIL;
    const int Lg = (64 - g + DIL - 1) / DIL;
    int s0 = ii - K / 2; if (s0 < 0) s0 = 0; if (s0 > Lg - K) s0 = Lg - K;
    #pragma unroll
    for (int q = 0; q < K; ++q) { nw[q] = g + (s0 + q) * DIL; bw[q] = s0 + q - ii + (K - 1); }
  }

  const int p = bb * 4096 + h * 64 + w;
  const unsigned short* qp = qkv + (size_t)p * 576 + branch * 192 + head * 32;
  float q[32];
  #pragma unroll
  for (int u = 0; u < 4; ++u) {
    uint4 v = *(const uint4*)(qp + u * 8);
    q[u*8+0] = bflo(v.x); q[u*8+1] = bfhi(v.x);
    q[u*8+2] = bflo(v.y); q[u*8+3] = bfhi(v.y);
    q[u*8+4] = bflo(v.z); q[u*8+5] = bfhi(v.z);
    q[u*8+6] = bflo(v.w); q[u*8+7] = bfhi(v.w);
  }
  float mx = -1e30f, l = 0.0f, acc[32];
  #pragma unroll
  for (int d = 0; d < 32; ++d) acc[d] = 0.0f;

  const unsigned short* kvb = qkv + (size_t)bb * 4096 * 576 + branch * 192 + 64 + head * 32;

  for (int kh = 0; kh < K; ++kh) {      // rolled: scalar recompute, no runtime-indexed arrays
    const int nhv = gh + (s0h + kh) * DIL;
    const int bhv = s0h + kh - iih + (K - 1);
    const float* rrow = &rs[bhv * RW];
    const int ho = nhv * 64;
    #pragma unroll
    for (int kw = 0; kw < K; ++kw) {
      const unsigned short* kp = kvb + (size_t)(ho + nw[kw]) * 576;
      float s = rrow[bw[kw]];
      #pragma unroll
      for (int u = 0; u < 4; ++u) {
        uint4 kv = *(const uint4*)(kp + u * 8);
        s += bflo(kv.x) * q[u*8+0] + bfhi(kv.x) * q[u*8+1]
           + bflo(kv.y) * q[u*8+2] + bfhi(kv.y) * q[u*8+3]
           + bflo(kv.z) * q[u*8+4] + bfhi(kv.z) * q[u*8+5]
           + bflo(kv.w) * q[u*8+6] + bfhi(kv.w) * q[u*8+7];
      }
      const float mn = fmaxf(mx, s);
      const float corr = __expf(mx - mn);
      const float pw = __expf(s - mn);
      mx = mn;
      l = l * corr + pw;
      #pragma unroll
      for (int u = 0; u < 4; ++u) {
        uint4 vv = *(const uint4*)(kp + 64 + u * 8);
        acc[u*8+0] = acc[u*8+0] * corr + pw * bflo(vv.x);
        acc[u*8+1] = acc[u*8+1] * corr + pw * bfhi(vv.x);
        acc[u*8+2] = acc[u*8+2] * corr + pw * bflo(vv.y);
        acc[u*8+3] = acc[u*8+3] * corr + pw * bfhi(vv.y);
        acc[u*8+4] = acc[u*8+4] * corr + pw * bflo(vv.z);
        acc[u*8+5] = acc[u*8+5] * corr + pw * bfhi(vv.z);
        acc[u*8+6] = acc[u*8+6] * corr + pw * bflo(vv.w);
        acc[u*8+7] = acc[u*8+7] * corr + pw * bfhi(vv.w);
      }
    }
  }
  const float inv = 1.0f / l;
  unsigned short* op = yo + (size_t)p * 192 + branch * 64 + head * 32;
  #pragma unroll
  for (int u = 0; u < 4; ++u) {
    uint4 pk;
    pk.x = packbf2(acc[u*8+0] * inv, acc[u*8+1] * inv);
    pk.y = packbf2(acc[u*8+2] * inv, acc[u*8+3] * inv);
    pk.z = packbf2(acc[u*8+4] * inv, acc[u*8+5] * inv);
    pk.w = packbf2(acc[u*8+6] * inv, acc[u*8+7] * inv);
    *(uint4*)(op + u * 8) = pk;
  }
}

__global__ __launch_bounds__(256) void natten_all(
    const unsigned short* __restrict__ qkv,
    const float* __restrict__ rpb0, const float* __restrict__ rpb1,
    const float* __restrict__ rpb2, unsigned short* __restrict__ yo) {
  if (blockIdx.z == 0)      natten_branch<3, 1>(qkv, rpb0, yo, 0);
  else if (blockIdx.z == 1) natten_branch<5, 2>(qkv, rpb1, yo, 1);
  else                      natten_branch<7, 3>(qkv, rpb2, yo, 2);
}

// ---------------- kernel 3: proj GEMM (computes C^T for coalesced NCHW stores) ----------------
// out[b][c][hw] = proj_w[c][:] . y[pixel][:] + proj_b[c]
__global__ __launch_bounds__(256) void proj_gemm(
    const unsigned short* __restrict__ y, const float* __restrict__ w,
    const float* __restrict__ bias, float* __restrict__ out) {
  __shared__ unsigned short Al[64 * LDK];  // A = proj_w rows (out channels x K)
  __shared__ unsigned short Bl[64 * LDK];  // B^T = y rows (pixels x K)
  const int t = threadIdx.x;
  const int tp = blockIdx.x;       // 512 pixel tiles
  const int c0 = blockIdx.y * 64;  // 3 out-channel tiles

  for (int j = 0; j < 3072; j += 256) {
    int idx = j + t;
    int n = idx / 48, k = (idx % 48) * 4;
    const float4 wv = *(const float4*)(w + (c0 + n) * 192 + k);
    ushort4 pk;
    pk.x = f2bf(wv.x); pk.y = f2bf(wv.y); pk.z = f2bf(wv.z); pk.w = f2bf(wv.w);
    *(ushort4*)&Al[n * LDK + k] = pk;
  }
  const unsigned short* ybp = y + (size_t)(tp * 64) * 192;
  for (int j = 0; j < 1536; j += 256) {
    int idx = j + t;
    int m = idx / 24, k8 = (idx % 24) * 8;
    *(uint4*)&Bl[m * LDK + k8] = *(const uint4*)(ybp + m * 192 + k8);
  }
  __syncthreads();

  const int lane = t & 63, wid = t >> 6;
  const int wm = (wid >> 1) * 32, wn = (wid & 1) * 32;
  const int lr = lane & 15, kb = (lane >> 4) * 8;
  f32x4 acc[2][2];
  #pragma unroll
  for (int i = 0; i < 2; ++i)
    #pragma unroll
    for (int j = 0; j < 2; ++j)
      #pragma unroll
      for (int r = 0; r < 4; ++r) acc[i][j][r] = 0.0f;

  #pragma unroll
  for (int kk = 0; kk < 192; kk += 32) {
    bf16x8 a0 = *(const bf16x8*)&Al[(wm + lr) * LDK + kk + kb];
    bf16x8 a1 = *(const bf16x8*)&Al[(wm + 16 + lr) * LDK + kk + kb];
    bf16x8 b0 = *(const bf16x8*)&Bl[(wn + lr) * LDK + kk + kb];
    bf16x8 b1 = *(const bf16x8*)&Bl[(wn + 16 + lr) * LDK + kk + kb];
    acc[0][0] = __builtin_amdgcn_mfma_f32_16x16x32_bf16(a0, b0, acc[0][0], 0, 0, 0);
    acc[0][1] = __builtin_amdgcn_mfma_f32_16x16x32_bf16(a0, b1, acc[0][1], 0, 0, 0);
    acc[1][0] = __builtin_amdgcn_mfma_f32_16x16x32_bf16(a1, b0, acc[1][0], 0, 0, 0);
    acc[1][1] = __builtin_amdgcn_mfma_f32_16x16x32_bf16(a1, b1, acc[1][1], 0, 0, 0);
  }

  const int gp = tp * 64;
  const int bb = gp >> 12, hw0 = gp & 4095;
  float* op = out + (size_t)bb * 192 * 4096 + hw0;
  const int r0 = (lane >> 4) * 4;
  #pragma unroll
  for (int i = 0; i < 2; ++i)
    #pragma unroll
    for (int j = 0; j < 2; ++j) {
      int m = wn + j * 16 + lr;  // pixel (D col)
      #pragma unroll
      for (int r = 0; r < 4; ++r) {
        int c = c0 + wm + i * 16 + r0 + r;  // out channel (D row)
        op[(size_t)c * 4096 + m] = acc[i][j][r] + bias[c];
      }
    }
}

// ---------------- launch ----------------
extern "C" void kernel_launch(void* const* d_in, const int* in_sizes, int n_in,
                              void* d_out, int out_size, void* d_ws, size_t ws_size,
                              hipStream_t stream) {
  const float* x      = (const float*)d_in[0];
  const float* qkv_w  = (const float*)d_in[1];
  const float* qkv_b  = (const float*)d_in[2];
  const float* proj_w = (const float*)d_in[3];
  const float* proj_b = (const float*)d_in[4];
  const float* rpb0   = (const float*)d_in[5];
  const float* rpb1   = (const float*)d_in[6];
  const float* rpb2   = (const float*)d_in[7];

  unsigned short* qkv = (unsigned short*)d_ws;                        // 32768*576 bf16 = 37.75 MB
  unsigned short* yb  = (unsigned short*)d_ws + (size_t)32768 * 576;  // 32768*192 bf16 = 12.58 MB
  float* out = (float*)d_out;

  qkv_gemm<<<dim3(512, 9), 256, 0, stream>>>(x, qkv_w, qkv_b, qkv);
  natten_all<<<dim3(16, 16, 3), 256, 0, stream>>>(qkv, rpb0, rpb1, rpb2, yb);
  proj_gemm<<<dim3(512, 3), 256, 0, stream>>>(yb, proj_w, proj_b, out);
}